// Round 1
// 953.125 us; speedup vs baseline: 1.1878x; 1.1878x over previous
//
#include <hip/hip_runtime.h>

// 2-layer tanh RNN (B=4096, T=512, D=30) + MLP head (30->15->15->1), fp32.
//
// TWO-PASS: kernel A precomputes xw = Wih1*x + (bih1+bhh1) for all 2.1M rows
// (memory-bound); kernel B runs the recurrence + head reading xw.
//
// R9: kernel B is VALU-throughput-bound (88% VALUBusy, ~800 VALU cyc/step).
// The head is feed-forward, so pipeline it one step behind and FUSE phase 3
// (W2*v1) into phase 2's FMA slots: lanes 16..30 receive v1_{t-1}[k] via
// ds_bpermute (DS pipe, idle) while other lanes receive h2_t[k]. One tanh(P2)
// then yields v1_t (lanes 0..14) AND v2_{t-1} (lanes 16..30). Deletes
// 15 readlanes + 15 FMAs + 1 tanh per step from the VALU pipe; per-lane
// accumulation order is bit-identical to the old phase2+phase3.

namespace {
constexpr int T = 512;
constexpr int D = 30;   // hidden size
constexpr int H = 15;   // head hidden size

// tanh(x) = 1 - 2/(exp(2x)+1): NaN-free at +/-inf, ~1e-6 abs err.
__device__ __forceinline__ float fast_tanh(float x) {
  float e = __expf(2.0f * x);
  return 1.0f - 2.0f * __builtin_amdgcn_rcpf(e + 1.0f);
}

// Broadcast lane `lane`'s value (SGPR result, scalar operand of v_fma).
__device__ __forceinline__ float bcast(float v, int lane) {
  return __int_as_float(__builtin_amdgcn_readlane(__float_as_int(v), lane));
}

// Per-lane gather: pull lane (byteaddr>>2)'s value of v (VGPR result, DS pipe).
__device__ __forceinline__ float lanepull(float v, int byteaddr) {
  return __int_as_float(
      __builtin_amdgcn_ds_bpermute(byteaddr, __float_as_int(v)));
}

// Non-volatile pre-loop pin: value must materialize in a register here.
#define PIN(v) asm("" : "+v"(v))
}  // namespace

// ---------------------------------------------------------------------------
// Kernel A: xw[row,:] = Wih1 . x[row,:] + (bih1+bhh1), row = b*T+t.
// 256 rows/block. Coalesced IO through an LDS tile (stride-31 pad: 31*t+k
// mod 32 is distinct across a wave -> conflict-free row reads).
// ---------------------------------------------------------------------------
__global__ __launch_bounds__(256) void xw_precompute(
    const float* __restrict__ x, const float* __restrict__ Wih1,
    const float* __restrict__ bih1, const float* __restrict__ bhh1,
    float* __restrict__ xw) {
  __shared__ float xs[256 * 31];
  const int tid = threadIdx.x;
  const long base = (long)blockIdx.x * (256 * 30);  // tile element offset

  // stage in: 15 x coalesced float2 (wave reads 512B contiguous per iter)
#pragma unroll
  for (int k = 0; k < 15; ++k) {
    const int idx = k * 512 + tid * 2;       // even -> col even, col+1 same row
    const float2 v = *(const float2*)(x + base + idx);
    const int row = idx / 30;                // magic-mul
    const int col = idx - row * 30;
    xs[row * 31 + col] = v.x;
    xs[row * 31 + col + 1] = v.y;
  }
  __syncthreads();

  // compute: thread t owns row t (conflict-free LDS reads)
  float xv[D];
#pragma unroll
  for (int k = 0; k < D; ++k) xv[k] = xs[tid * 31 + k];
#pragma unroll
  for (int i = 0; i < D; ++i) {
    float a = bih1[i] + bhh1[i];             // uniform -> s_load
#pragma unroll
    for (int k = 0; k < D; ++k) a = fmaf(Wih1[i * D + k], xv[k], a);
    xs[tid * 31 + i] = a;                    // own-row writeback (no race)
  }
  __syncthreads();

  // stage out: coalesced float2 stores
#pragma unroll
  for (int k = 0; k < 15; ++k) {
    const int idx = k * 512 + tid * 2;
    const int row = idx / 30;
    const int col = idx - row * 30;
    float2 o;
    o.x = xs[row * 31 + col];
    o.y = xs[row * 31 + col + 1];
    *(float2*)(xw + base + idx) = o;
  }
}

// ---------------------------------------------------------------------------
// Kernel B: recurrence + pipelined head, reading precomputed xw.
// One wave per chain, 4096 blocks.
//  phase 1: readlane-broadcast h1 -> lower rec1 (Whh1.h1), upper Wih2.h1.
//  phase 2 (fused): k<15 via ds_bpermute of g=(lane<16 ? v1_prev : h2),
//                   k>=15 via readlane(h2). Computes W1.h2 (lanes 0..14),
//                   W2.v1_prev (lanes 16..30, bw[k>=15]=0 kills h2 terms),
//                   Whh2.h2 (upper). One tanh -> v1_t AND v2_{t-1}.
//  head: W3 reduce -> out[t-1]; carry-paired float2 stores + epilogue.
// ---------------------------------------------------------------------------
__global__ __attribute__((amdgpu_waves_per_eu(4, 4)))
__launch_bounds__(64) void rnn_head_rec(
    const float* __restrict__ xw,
    const float* __restrict__ Whh1,
    const float* __restrict__ Wih2, const float* __restrict__ Whh2,
    const float* __restrict__ bih2, const float* __restrict__ bhh2,
    const float* __restrict__ W1, const float* __restrict__ b1,
    const float* __restrict__ W2, const float* __restrict__ b2,
    const float* __restrict__ W3, const float* __restrict__ b3,
    float* __restrict__ out) {
  const int j = threadIdx.x;           // 0..63
  const bool lo = (j < 32);
  const int ju = j & 31;
  const int r = (ju < D) ? ju : (D - 1);  // clamped row index 0..29

  // ---- per-lane weight rows (60 total) ----
  float aw[D], bw[D];
  {
    const float* Ar = (lo ? Whh1 : Wih2) + r * D;
#pragma unroll
    for (int k = 0; k < D; ++k) aw[k] = Ar[k];
#pragma unroll
    for (int k = 0; k < D; ++k) {
      float v;
      if (!lo)
        v = Whh2[r * D + k];
      else if (j < H)
        v = W1[j * D + k];                 // lanes 0..14: W1 rows (-> v1)
      else if (j >= 16 && j < 31 && k < H)
        v = W2[(j - 16) * H + k];          // lanes 16..30: W2 rows (-> v2)
      else
        v = 0.0f;                          // lanes 15, 31: dead
      bw[k] = v;
    }
  }
#pragma unroll
  for (int k = 0; k < D; ++k) {
    PIN(aw[k]);
    PIN(bw[k]);
  }

  // phase-2 ds_bpermute byte addresses, k = 0..14:
  //  consumer lanes 16..31 pull lane k    (v1_{t-1} slot of g)
  //  all other lanes      pull lane 32+k (h2_t slot of g)
  int addr2[H];
  {
    const int abase = (j >= 16 && j < 32) ? 0 : 128;
#pragma unroll
    for (int k = 0; k < H; ++k) {
      addr2[k] = abase + 4 * k;
      PIN(addr2[k]);
    }
  }

  // biasA2m: layer-2 bias on upper lanes, 0 on lower (so rec1 stays pure).
  float biasA2m = lo ? 0.0f : (bih2[r] + bhh2[r]);
  // biasB: lanes 0..14 = b1, lanes 16..30 = b2, else 0 (keeps rec2 pure).
  float biasB = (j < H) ? b1[j] : ((j >= 16 && j < 31) ? b2[j - 16] : 0.0f);
  const bool mid = (j >= 16) && (j < 31);  // lanes holding W2/W3 (v2)
  float w3v = mid ? W3[j - 16] : 0.0f;
  const float sb3 = b3[0];
  PIN(biasA2m);
  PIN(biasB);
  PIN(w3v);

  const float* xr = xw + (long)blockIdx.x * (T * D);
  float* outp = out + (long)blockIdx.x * T;
  const int cj = r;  // per-lane xw slot (clamped; upper lanes mirror lower)

  // xw ping-pong: lane r holds xw_t[r]; prefetch distance 2 (~1000 cyc slack)
  float xvA = xr[cj];      // t = 0
  float xvB = xr[D + cj];  // t = 1

  float rec1 = 0.0f;  // Whh1*h1_{t-1}, valid on lower lanes
  float rec2 = 0.0f;  // Whh2*h2_{t-1}, valid on upper lanes
  float v1p = 0.0f;   // v1_{t-1}, valid on lanes 0..14 (0 before t=0)

  auto step = [&](float& xv, int tpre) -> float {
    // xw already holds Wih1.x + bih1 + bhh1
    const float h1 = fast_tanh(xv + rec1);  // valid on lanes 0..29

    // refill this buffer for step tpre (consumed 2 steps from now)
    xv = xr[(long)tpre * D + cj];

    // ---- phase 1: broadcast h1; lower->rec1_next, upper->layer2 preact ----
    float s1[D];
#pragma unroll
    for (int k = 0; k < D; ++k) s1[k] = bcast(h1, k);
    __builtin_amdgcn_sched_barrier(0);
    float p0 = biasA2m, p1 = 0.0f, p2 = 0.0f, p3 = 0.0f;  // 0 on lower
#pragma unroll
    for (int k = 0; k < D; ++k) {
      if ((k & 3) == 0)
        p0 = fmaf(aw[k], s1[k], p0);
      else if ((k & 3) == 1)
        p1 = fmaf(aw[k], s1[k], p1);
      else if ((k & 3) == 2)
        p2 = fmaf(aw[k], s1[k], p2);
      else
        p3 = fmaf(aw[k], s1[k], p3);
    }
    const float P1 = (p0 + p1) + (p2 + p3);
    rec1 = P1;                                // meaningful on lower (pure dot)
    const float h2 = fast_tanh(P1 + rec2);    // valid on lanes 32..61

    // ---- phase 2 (fused head): per-lane broadcast source ----
    const float g = (j < 16) ? v1p : h2;  // src lanes 0..14: v1p; 32..61: h2
    float bb[H];
#pragma unroll
    for (int k = 0; k < H; ++k) bb[k] = lanepull(g, addr2[k]);  // DS pipe
    float sh[D - H];
#pragma unroll
    for (int k = H; k < D; ++k) sh[k - H] = bcast(h2, 32 + k);  // VALU->SGPR
    __builtin_amdgcn_sched_barrier(0);
    float q0 = biasB, q1 = 0.0f, q2 = 0.0f, q3 = 0.0f;  // biasB==0 on upper
#pragma unroll
    for (int k = 0; k < D; ++k) {
      const float s = (k < H) ? bb[k] : sh[k - H];
      if ((k & 3) == 0)
        q0 = fmaf(bw[k], s, q0);
      else if ((k & 3) == 1)
        q1 = fmaf(bw[k], s, q1);
      else if ((k & 3) == 2)
        q2 = fmaf(bw[k], s, q2);
      else
        q3 = fmaf(bw[k], s, q3);
    }
    const float P2 = (q0 + q1) + (q2 + q3);
    rec2 = P2;                       // meaningful on upper (pure dot)
    const float tv = fast_tanh(P2);  // v1_t on lanes 0..14, v2_{t-1} on 16..30
    v1p = tv;

    // ---- head layer 3: reduce W3.v2_{t-1} within group [16,31] ----
    float pv = mid ? (w3v * tv) : 0.0f;  // cndmask kills garbage-lane values
    pv += __shfl_xor(pv, 8, 16);
    pv += __shfl_xor(pv, 4, 16);
    pv += __shfl_xor(pv, 2, 16);
    pv += __shfl_xor(pv, 1, 16);
    return pv;  // out[t-1] (pre-b3), valid on lanes 16..31
  };

  float carry = 0.0f;  // out[t] value awaiting its even-aligned pair store
  for (int t = 0; t < T; t += 2) {
    const float pA = step(xvA, (t + 2 < T) ? (t + 2) : (T - 1));  // out[t-1]
    if (t > 0 && j == 16) {
      float2 o;
      o.x = carry + sb3;  // out[t-2]
      o.y = pA + sb3;     // out[t-1]
      *(float2*)(outp + (t - 2)) = o;  // even offset -> 8B aligned
    }
    carry = step(xvB, (t + 3 < T) ? (t + 3) : (T - 1));  // out[t]
  }

  // ---- epilogue: head-only pass for out[T-1] from v1_{T-1} ----
  {
    float bb[H];
#pragma unroll
    for (int k = 0; k < H; ++k) bb[k] = lanepull(v1p, addr2[k]);
    float u0 = biasB, u1 = 0.0f, u2 = 0.0f, u3 = 0.0f;
#pragma unroll
    for (int k = 0; k < H; ++k) {
      if ((k & 3) == 0)
        u0 = fmaf(bw[k], bb[k], u0);
      else if ((k & 3) == 1)
        u1 = fmaf(bw[k], bb[k], u1);
      else if ((k & 3) == 2)
        u2 = fmaf(bw[k], bb[k], u2);
      else
        u3 = fmaf(bw[k], bb[k], u3);
    }
    const float v2 = fast_tanh((u0 + u1) + (u2 + u3));  // lanes 16..30
    float pv = mid ? (w3v * v2) : 0.0f;
    pv += __shfl_xor(pv, 8, 16);
    pv += __shfl_xor(pv, 4, 16);
    pv += __shfl_xor(pv, 2, 16);
    pv += __shfl_xor(pv, 1, 16);
    if (j == 16) {
      float2 o;
      o.x = carry + sb3;  // out[T-2]
      o.y = pv + sb3;     // out[T-1]
      *(float2*)(outp + (T - 2)) = o;
    }
  }
}

// ---------------------------------------------------------------------------
// Fallback (ws too small): R5's known-good fused kernel (1070 us).
// ---------------------------------------------------------------------------
__global__ __launch_bounds__(64, 3) void rnn_head_fused_fb(
    const float* __restrict__ x,
    const float* __restrict__ Wih1, const float* __restrict__ Whh1,
    const float* __restrict__ bih1, const float* __restrict__ bhh1,
    const float* __restrict__ Wih2, const float* __restrict__ Whh2,
    const float* __restrict__ bih2, const float* __restrict__ bhh2,
    const float* __restrict__ W1, const float* __restrict__ b1,
    const float* __restrict__ W2, const float* __restrict__ b2,
    const float* __restrict__ W3, const float* __restrict__ b3,
    float* __restrict__ out) {
  const int j = threadIdx.x;
  const bool lo = (j < 32);
  const int ju = j & 31;
  const int r = (ju < D) ? ju : (D - 1);

  float dk[D], aw[D], bw[D];
  {
    const float* Dr = Wih1 + r * D;
    const float* Ar = (lo ? Whh1 : Wih2) + r * D;
#pragma unroll
    for (int k = 0; k < D; ++k) {
      dk[k] = Dr[k];
      aw[k] = Ar[k];
    }
#pragma unroll
    for (int k = 0; k < D; ++k) {
      float v;
      if (!lo)
        v = Whh2[r * D + k];
      else if (j < H)
        v = W1[j * D + k];
      else if (j >= 16 && j < 31 && k < H)
        v = W2[(j - 16) * H + k];
      else
        v = 0.0f;
      bw[k] = v;
    }
  }
#pragma unroll
  for (int k = 0; k < D; ++k) {
    PIN(dk[k]);
    PIN(aw[k]);
    PIN(bw[k]);
  }

  float biasA = lo ? (bih1[r] + bhh1[r]) : (bih2[r] + bhh2[r]);
  float biasB = (j < H) ? b1[j] : ((j >= 16 && j < 31) ? b2[j - 16] : 0.0f);
  const bool mid = (j >= 16) && (j < 31);
  float w3v = mid ? W3[j - 16] : 0.0f;
  const float sb3 = b3[0];
  PIN(biasA);
  PIN(biasB);
  PIN(w3v);

  const float* xr = x + (long)blockIdx.x * (T * D);
  float* outp = out + (long)blockIdx.x * T;
  const int cj = r;

  float xvA = xr[cj];
  float xvB = xr[D + cj];
  float rec1 = 0.0f, rec2 = 0.0f;

  auto step = [&](float& xv, int tpre) -> float {
    float a0 = biasA, a1 = rec1, a2 = 0.0f, a3 = 0.0f;
#pragma unroll
    for (int k = 0; k < D; ++k) {
      const float s = bcast(xv, k);
      if ((k & 3) == 0)
        a0 = fmaf(dk[k], s, a0);
      else if ((k & 3) == 1)
        a1 = fmaf(dk[k], s, a1);
      else if ((k & 3) == 2)
        a2 = fmaf(dk[k], s, a2);
      else
        a3 = fmaf(dk[k], s, a3);
    }
    const float h1 = fast_tanh((a0 + a1) + (a2 + a3));
    xv = xr[(long)tpre * D + cj];

    float p0 = 0.0f, p1 = 0.0f, p2 = 0.0f, p3 = 0.0f;
#pragma unroll
    for (int k = 0; k < D; ++k) {
      const float s = bcast(h1, k);
      if ((k & 3) == 0)
        p0 = fmaf(aw[k], s, p0);
      else if ((k & 3) == 1)
        p1 = fmaf(aw[k], s, p1);
      else if ((k & 3) == 2)
        p2 = fmaf(aw[k], s, p2);
      else
        p3 = fmaf(aw[k], s, p3);
    }
    const float P1 = (p0 + p1) + (p2 + p3);
    rec1 = P1;
    const float h2 = fast_tanh(P1 + biasA + rec2);

    float q0 = biasB, q1 = 0.0f, q2 = 0.0f, q3 = 0.0f;
#pragma unroll
    for (int k = 0; k < D; ++k) {
      const float s = bcast(h2, 32 + k);
      if ((k & 3) == 0)
        q0 = fmaf(bw[k], s, q0);
      else if ((k & 3) == 1)
        q1 = fmaf(bw[k], s, q1);
      else if ((k & 3) == 2)
        q2 = fmaf(bw[k], s, q2);
      else
        q3 = fmaf(bw[k], s, q3);
    }
    const float P2 = (q0 + q1) + (q2 + q3);
    rec2 = P2;
    const float v1 = fast_tanh(P2);

    float u0 = biasB, u1 = 0.0f, u2 = 0.0f, u3 = 0.0f;
#pragma unroll
    for (int k = 0; k < H; ++k) {
      const float s = bcast(v1, k);
      if ((k & 3) == 0)
        u0 = fmaf(bw[k], s, u0);
      else if ((k & 3) == 1)
        u1 = fmaf(bw[k], s, u1);
      else if ((k & 3) == 2)
        u2 = fmaf(bw[k], s, u2);
      else
        u3 = fmaf(bw[k], s, u3);
    }
    const float v2 = fast_tanh((u0 + u1) + (u2 + u3));

    float pv = mid ? (w3v * v2) : 0.0f;
    pv += __shfl_xor(pv, 8, 16);
    pv += __shfl_xor(pv, 4, 16);
    pv += __shfl_xor(pv, 2, 16);
    pv += __shfl_xor(pv, 1, 16);
    return pv;
  };

  for (int t = 0; t < T; t += 2) {
    const float pA = step(xvA, (t + 2 < T) ? (t + 2) : (T - 1));
    const float pB = step(xvB, (t + 3 < T) ? (t + 3) : (T - 1));
    if (j == 16) {
      float2 o;
      o.x = pA + sb3;
      o.y = pB + sb3;
      *(float2*)(outp + t) = o;
    }
  }
}

extern "C" void kernel_launch(void* const* d_in, const int* in_sizes, int n_in,
                              void* d_out, int out_size, void* d_ws,
                              size_t ws_size, hipStream_t stream) {
  const float* x = (const float*)d_in[0];
  const float* Wih1 = (const float*)d_in[1];
  const float* Whh1 = (const float*)d_in[2];
  const float* bih1 = (const float*)d_in[3];
  const float* bhh1 = (const float*)d_in[4];
  const float* Wih2 = (const float*)d_in[5];
  const float* Whh2 = (const float*)d_in[6];
  const float* bih2 = (const float*)d_in[7];
  const float* bhh2 = (const float*)d_in[8];
  const float* W1 = (const float*)d_in[9];
  const float* b1 = (const float*)d_in[10];
  const float* W2 = (const float*)d_in[11];
  const float* b2 = (const float*)d_in[12];
  const float* W3 = (const float*)d_in[13];
  const float* b3 = (const float*)d_in[14];

  const int B = in_sizes[0] / (T * D);         // 4096 chains
  const size_t xw_bytes = (size_t)B * T * D * sizeof(float);  // 252 MB

  if (ws_size >= xw_bytes) {
    float* xw = (float*)d_ws;
    const long rows = (long)B * T;             // 2,097,152 = 8192 * 256
    hipLaunchKernelGGL(xw_precompute, dim3(rows / 256), dim3(256), 0, stream,
                       x, Wih1, bih1, bhh1, xw);
    hipLaunchKernelGGL(rnn_head_rec, dim3(B), dim3(64), 0, stream, xw, Whh1,
                       Wih2, Whh2, bih2, bhh2, W1, b1, W2, b2, W3, b3,
                       (float*)d_out);
  } else {
    hipLaunchKernelGGL(rnn_head_fused_fb, dim3(B), dim3(64), 0, stream, x,
                       Wih1, Whh1, bih1, bhh1, Wih2, Whh2, bih2, bhh2, W1, b1,
                       W2, b2, W3, b3, (float*)d_out);
  }
}